// Round 4
// baseline (3068.106 us; speedup 1.0000x reference)
//
#include <hip/hip_runtime.h>

// StructureModule on MI355X — round 4: fused attention (softmax+pair+scalar in
// one kernel, wave-per-3-heads softmax, MFMA pair from LDS), coord fused in LN2.

constexpr int N    = 512;
constexpr int CS   = 384;
constexpr int CZ   = 128;
constexpr int CH   = 16;
constexpr int H    = 12;
constexpr int L    = 8;
constexpr int RECY = 2;
constexpr int HCH  = H * CH;        // 192
constexpr int QKVN = 3 * HCH;       // 576
constexpr int OD   = H * (CH + CZ); // 1728
constexpr int FF   = 4 * CS;        // 1536
constexpr int MB   = 96;            // bias rows = L*H
constexpr long long NN2 = (long long)N * N;

typedef __bf16 bf16x8 __attribute__((ext_vector_type(8)));
typedef float  f32x4  __attribute__((ext_vector_type(4)));

__device__ __forceinline__ ushort f2bf(float f) {
    uint u = __builtin_bit_cast(uint, f);
    return (ushort)((u + 0x7fffu + ((u >> 16) & 1u)) >> 16);   // RNE
}
__device__ __forceinline__ float bf2f(ushort h) {
    uint u = ((uint)h) << 16;
    return __builtin_bit_cast(float, u);
}

// ----------------------------------------------------- init s (f32 + bf16 copy)
__global__ __launch_bounds__(256) void init_s(
    const float* __restrict__ s_in, float* __restrict__ scur, ushort* __restrict__ sbf)
{
    int i = blockIdx.x * 256 + threadIdx.x;
    float v = s_in[i];
    scur[i] = v;
    sbf[i]  = f2bf(v);
}

// ------------------------------------------------------------- pack bq|bk|bv
__global__ __launch_bounds__(256) void pack_bqkv(
    const float* __restrict__ bq, const float* __restrict__ bk,
    const float* __restrict__ bv, float* __restrict__ bqkv)
{
    int idx = blockIdx.x * 256 + threadIdx.x;
    if (idx >= L * QKVN) return;
    int n = idx % QKVN, l = idx / QKVN;
    int sel = n / HCH, nn = n % HCH;
    const float* bp = sel == 0 ? bq : (sel == 1 ? bk : bv);
    bqkv[idx] = bp[l * HCH + nn];
}

// ---------------------- pack Wq|Wk|Wv transposed to bf16 [l][n][k] (n-major)
__global__ __launch_bounds__(256) void pack_qkv_t(
    const float* __restrict__ Wq, const float* __restrict__ Wk,
    const float* __restrict__ Wv, ushort* __restrict__ WqkvT)
{
    __shared__ float tile[32][33];
    const int l = blockIdx.z;
    const int k0 = blockIdx.x * 32, n0 = blockIdx.y * 32;
    const int tx = threadIdx.x & 31, ty = threadIdx.x >> 5;
    const int sel = n0 / HCH;
    const int nn0 = n0 - sel * HCH;
    const float* W = sel == 0 ? Wq : (sel == 1 ? Wk : Wv);
    #pragma unroll
    for (int r = 0; r < 32; r += 8)
        tile[ty + r][tx] = W[((size_t)l * CS + k0 + ty + r) * HCH + nn0 + tx];
    __syncthreads();
    #pragma unroll
    for (int r = 0; r < 32; r += 8)
        WqkvT[((size_t)l * QKVN + n0 + ty + r) * CS + k0 + tx] = f2bf(tile[tx][ty + r]);
}

// ------------- generic transpose+convert: (G,K,Nn) f32 -> (G,Nn,K) bf16
__global__ __launch_bounds__(256) void transpose_w(
    const float* __restrict__ in, ushort* __restrict__ out, int K, int Nn)
{
    __shared__ float tile[32][33];
    const int l = blockIdx.z;
    const float* ip = in + (size_t)l * K * Nn;
    ushort* op = out + (size_t)l * K * Nn;
    const int k0 = blockIdx.x * 32, n0 = blockIdx.y * 32;
    const int tx = threadIdx.x & 31, ty = threadIdx.x >> 5;
    #pragma unroll
    for (int r = 0; r < 32; r += 8)
        tile[ty + r][tx] = ip[(size_t)(k0 + ty + r) * Nn + n0 + tx];
    __syncthreads();
    #pragma unroll
    for (int r = 0; r < 32; r += 8)
        op[(size_t)(n0 + ty + r) * K + k0 + tx] = f2bf(tile[tx][ty + r]);
}

// -------------------------------------- WbT[m=l*12+h][c] = Wb[l][c][h] (bf16)
__global__ __launch_bounds__(256) void pack_wbt(
    const float* __restrict__ Wb, ushort* __restrict__ WbT)
{
    int idx = blockIdx.x * 256 + threadIdx.x;     // MB*CZ = 12288
    int m = idx >> 7, c = idx & 127;
    int l = m / H, h = m % H;
    WbT[idx] = f2bf(Wb[((size_t)l * CZ + c) * H + h]);
}

// -------------------- bias_all[m][ij] = sum_c WbT[m][c]*z[ij][c] + bb[m]
__global__ __launch_bounds__(256) void bias_gemm(
    const ushort* __restrict__ WbT, const float* __restrict__ z,
    const float* __restrict__ bb, ushort* __restrict__ bias_all)
{
    const int w = threadIdx.x >> 6, lane = threadIdx.x & 63;
    const int lm = lane & 15, kg = lane >> 4;
    const size_t ij0 = (size_t)blockIdx.x * 256 + (size_t)w * 64;
    __shared__ float bbs[MB];
    if (threadIdx.x < MB) bbs[threadIdx.x] = bb[threadIdx.x];
    __syncthreads();
    f32x4 acc[6][4];
    #pragma unroll
    for (int mt = 0; mt < 6; mt++)
        #pragma unroll
        for (int nt = 0; nt < 4; nt++) acc[mt][nt] = (f32x4){0.f, 0.f, 0.f, 0.f};
    #pragma unroll
    for (int kc = 0; kc < 4; kc++) {
        const int k = kc * 32 + kg * 8;
        bf16x8 b[4];
        #pragma unroll
        for (int nt = 0; nt < 4; nt++) {
            const float* zp = z + (ij0 + nt * 16 + lm) * CZ + k;
            float4 z0 = *(const float4*)zp, z1 = *(const float4*)(zp + 4);
            b[nt][0] = (__bf16)z0.x; b[nt][1] = (__bf16)z0.y;
            b[nt][2] = (__bf16)z0.z; b[nt][3] = (__bf16)z0.w;
            b[nt][4] = (__bf16)z1.x; b[nt][5] = (__bf16)z1.y;
            b[nt][6] = (__bf16)z1.z; b[nt][7] = (__bf16)z1.w;
        }
        #pragma unroll
        for (int mt = 0; mt < 6; mt++) {
            bf16x8 a = *(const bf16x8*)(WbT + (size_t)(mt * 16 + lm) * CZ + k);
            #pragma unroll
            for (int nt = 0; nt < 4; nt++)
                acc[mt][nt] = __builtin_amdgcn_mfma_f32_16x16x32_bf16(a, b[nt], acc[mt][nt], 0, 0, 0);
        }
    }
    #pragma unroll
    for (int mt = 0; mt < 6; mt++)
        #pragma unroll
        for (int nt = 0; nt < 4; nt++)
            #pragma unroll
            for (int r = 0; r < 4; r++) {
                int m = mt * 16 + kg * 4 + r;
                bias_all[(size_t)m * NN2 + ij0 + nt * 16 + lm] = f2bf(acc[mt][nt][r] + bbs[m]);
            }
}

// ----------------------------------------------------------- bf16 MFMA GEMM
__global__ __launch_bounds__(256) void gemm_bf16(
    const ushort* __restrict__ A, const ushort* __restrict__ Bt,
    const float* __restrict__ bias, float* __restrict__ C, ushort* __restrict__ Cbf,
    int M, int Nn, int K, int kper, int relu)
{
    const int w = threadIdx.x >> 6, lane = threadIdx.x & 63;
    const int lm = lane & 15, kg = lane >> 4;
    const int m0 = blockIdx.y * 64 + w * 16;
    const int n0 = blockIdx.x * 64;
    const int kbeg = blockIdx.z * kper;
    const ushort* Ap  = A  + (size_t)(m0 + lm) * K + kbeg + kg * 8;
    const ushort* Bp  = Bt + (size_t)(n0 + lm) * K + kbeg + kg * 8;
    f32x4 acc[4];
    #pragma unroll
    for (int ct = 0; ct < 4; ct++) acc[ct] = (f32x4){0.f, 0.f, 0.f, 0.f};
    for (int k = 0; k < kper; k += 32) {
        bf16x8 a = *(const bf16x8*)(Ap + k);
        #pragma unroll
        for (int ct = 0; ct < 4; ct++) {
            bf16x8 b = *(const bf16x8*)(Bp + (size_t)ct * 16 * K + k);
            acc[ct] = __builtin_amdgcn_mfma_f32_16x16x32_bf16(a, b, acc[ct], 0, 0, 0);
        }
    }
    float* Cz = C ? C + (size_t)blockIdx.z * M * Nn : nullptr;
    #pragma unroll
    for (int ct = 0; ct < 4; ct++) {
        int col = n0 + ct * 16 + lm;
        float bs = bias ? bias[col] : 0.f;
        #pragma unroll
        for (int r = 0; r < 4; r++) {
            int row = m0 + kg * 4 + r;
            float v = acc[ct][r] + bs;
            if (relu) v = fmaxf(v, 0.f);
            if (Cz)  Cz[(size_t)row * Nn + col] = v;
            if (Cbf) Cbf[(size_t)row * Nn + col] = f2bf(v);
        }
    }
}

// ---------------- fused attention: softmax + pair(MFMA) + scalar, one block/i
// Stage 1: wave w owns heads w*3..w*3+2, lane ln owns j = m*64+ln (m=0..7);
//          wave-local reductions, exp weights -> LDS sw[16][520] bf16 (rows
//          12..15 zeroed; +8 pad -> 2-way LDS conflicts only, free).
// Stage 2: pair[h][c] via mfma_16x16x32: A = sw rows (h), B = z_t[i] rows (c);
//          wave w covers c-tiles w*2, w*2+1; epilogue scales by inv_s[h].
// Stage 3: scalar[h][c] via VALU: v[j][h*16+c] reads are full 64B lines, L2-hot.
__global__ __launch_bounds__(256) void attn_fused(
    const float* __restrict__ qkv, const ushort* __restrict__ bias_l,
    const float* __restrict__ coords, const ushort* __restrict__ z_t,
    ushort* __restrict__ obuf)
{
    const int i = blockIdx.x, t = threadIdx.x;
    const int w = t >> 6, ln = t & 63;
    __shared__ __align__(16) float sq[HCH];
    __shared__ float sci[3];
    __shared__ float inv_s[H];
    __shared__ __align__(16) ushort sw[16][520];
    if (t < HCH) sq[t] = qkv[(size_t)i * QKVN + t] * 0.25f;   // 1/sqrt(16)
    if (t >= 200 && t < 203) sci[t - 200] = coords[i * 3 + (t - 200)];
    {   // zero A-rows 12..15 (4*512 entries / 256 threads = 8 each)
        int base = t * 8;
        int hz = 12 + (base >> 9), jz = base & 511;
        #pragma unroll
        for (int e = 0; e < 8; e++) sw[hz][jz + e] = 0;
    }
    __syncthreads();
    // multiscale term for this lane's 8 j's (depends on j only)
    float ms[8];
    #pragma unroll
    for (int m = 0; m < 8; m++) {
        int j = m * 64 + ln;
        float dx = sci[0] - coords[j * 3 + 0];
        float dy = sci[1] - coords[j * 3 + 1];
        float dz = sci[2] - coords[j * 3 + 2];
        float d2 = dx * dx + dy * dy + dz * dz;
        ms[m] = d2 <= 25.f ? 1.f : (d2 <= 225.f ? 0.3f : 0.05f);
    }
    #pragma unroll
    for (int hh = 0; hh < 3; hh++) {
        const int h = w * 3 + hh;
        float4 q0 = *(const float4*)&sq[h * 16 + 0];
        float4 q1 = *(const float4*)&sq[h * 16 + 4];
        float4 q2 = *(const float4*)&sq[h * 16 + 8];
        float4 q3 = *(const float4*)&sq[h * 16 + 12];
        float lg[8];
        #pragma unroll
        for (int m = 0; m < 8; m++) {
            int j = m * 64 + ln;
            const float4* kp = (const float4*)(qkv + (size_t)j * QKVN + HCH + h * 16);
            float4 k0 = kp[0], k1 = kp[1], k2 = kp[2], k3 = kp[3];
            float d = q0.x * k0.x + q0.y * k0.y + q0.z * k0.z + q0.w * k0.w
                    + q1.x * k1.x + q1.y * k1.y + q1.z * k1.z + q1.w * k1.w
                    + q2.x * k2.x + q2.y * k2.y + q2.z * k2.z + q2.w * k2.w
                    + q3.x * k3.x + q3.y * k3.y + q3.z * k3.z + q3.w * k3.w;
            lg[m] = d + bf2f(bias_l[(size_t)h * NN2 + (size_t)i * N + j]) + ms[m];
        }
        float mx = lg[0];
        #pragma unroll
        for (int m = 1; m < 8; m++) mx = fmaxf(mx, lg[m]);
        #pragma unroll
        for (int off = 32; off > 0; off >>= 1) mx = fmaxf(mx, __shfl_down(mx, off));
        mx = __shfl(mx, 0);
        float e[8], sm = 0.f;
        #pragma unroll
        for (int m = 0; m < 8; m++) { e[m] = __expf(lg[m] - mx); sm += e[m]; }
        #pragma unroll
        for (int off = 32; off > 0; off >>= 1) sm += __shfl_down(sm, off);
        sm = __shfl(sm, 0);
        if (ln == 0) inv_s[h] = 1.f / sm;
        #pragma unroll
        for (int m = 0; m < 8; m++) sw[h][m * 64 + ln] = f2bf(e[m]);
    }
    __syncthreads();
    // ---- stage 2: pair via MFMA ----
    const int lm = ln & 15, kg = ln >> 4;
    f32x4 acc[2];
    acc[0] = (f32x4){0.f, 0.f, 0.f, 0.f};
    acc[1] = (f32x4){0.f, 0.f, 0.f, 0.f};
    const ushort* zb = z_t + (size_t)i * CZ * N;
    for (int k = 0; k < N; k += 32) {
        bf16x8 a = *(const bf16x8*)&sw[lm][k + kg * 8];
        #pragma unroll
        for (int c2 = 0; c2 < 2; c2++) {
            int c0 = (w * 2 + c2) * 16;
            bf16x8 b = *(const bf16x8*)(zb + (size_t)(c0 + lm) * N + k + kg * 8);
            acc[c2] = __builtin_amdgcn_mfma_f32_16x16x32_bf16(a, b, acc[c2], 0, 0, 0);
        }
    }
    if (kg < 3) {
        #pragma unroll
        for (int c2 = 0; c2 < 2; c2++)
            #pragma unroll
            for (int r = 0; r < 4; r++) {
                int h = kg * 4 + r;
                int c = (w * 2 + c2) * 16 + lm;
                obuf[(size_t)i * OD + h * 144 + 16 + c] = f2bf(acc[c2][r] * inv_s[h]);
            }
    }
    // ---- stage 3: scalar via VALU ----
    if (t < HCH) {
        const int h = t >> 4, c = t & 15;
        const float* vp = qkv + 2 * HCH + h * 16 + c;
        float a = 0.f;
        #pragma unroll 4
        for (int j = 0; j < N; j++) a += bf2f(sw[h][j]) * vp[(size_t)j * QKVN];
        obuf[(size_t)i * OD + h * 144 + c] = f2bf(a * inv_s[h]);
    }
}

// -- s = LayerNorm(s + sum_p x[p] + gemm_bias)*g + b (+bf16 copy)
// -- optional fused coords += (s_new @ Wu + bu)[:3]
__global__ __launch_bounds__(128) void ln_residual(
    const float* __restrict__ x, int parts, const float* __restrict__ gb,
    float* __restrict__ s, ushort* __restrict__ sbf,
    const float* __restrict__ g, const float* __restrict__ b,
    const float* __restrict__ Wu_l, const float* __restrict__ bu_l,
    float* __restrict__ coords)
{
    const int i = blockIdx.x, t = threadIdx.x;
    __shared__ float red[4];
    __shared__ float red2[6];
    float v[3];
    float sum = 0.f;
    #pragma unroll
    for (int e = 0; e < 3; e++) {
        int c = t + e * 128;
        float a = s[(size_t)i * CS + c] + gb[c];
        for (int p = 0; p < parts; p++) a += x[(size_t)p * N * CS + (size_t)i * CS + c];
        v[e] = a; sum += a;
    }
    #pragma unroll
    for (int off = 32; off > 0; off >>= 1) sum += __shfl_down(sum, off);
    if ((t & 63) == 0) red[t >> 6] = sum;
    __syncthreads();
    float mu = (red[0] + red[1]) * (1.f / CS);
    float vs = 0.f;
    #pragma unroll
    for (int e = 0; e < 3; e++) { float d = v[e] - mu; vs += d * d; }
    #pragma unroll
    for (int off = 32; off > 0; off >>= 1) vs += __shfl_down(vs, off);
    if ((t & 63) == 0) red[2 + (t >> 6)] = vs;
    __syncthreads();
    float inv = rsqrtf((red[2] + red[3]) * (1.f / CS) + 1e-5f);
    float a3[3] = {0.f, 0.f, 0.f};
    #pragma unroll
    for (int e = 0; e < 3; e++) {
        int c = t + e * 128;
        float o = (v[e] - mu) * inv * g[c] + b[c];
        s[(size_t)i * CS + c]   = o;
        sbf[(size_t)i * CS + c] = f2bf(o);
        if (Wu_l) {
            #pragma unroll
            for (int o3 = 0; o3 < 3; o3++) a3[o3] += o * Wu_l[c * 6 + o3];
        }
    }
    if (Wu_l) {
        #pragma unroll
        for (int o3 = 0; o3 < 3; o3++)
            #pragma unroll
            for (int off = 32; off > 0; off >>= 1) a3[o3] += __shfl_down(a3[o3], off);
        if ((t & 63) == 0) {
            #pragma unroll
            for (int o3 = 0; o3 < 3; o3++) red2[(t >> 6) * 3 + o3] = a3[o3];
        }
        __syncthreads();
        if (t == 0) {
            #pragma unroll
            for (int o3 = 0; o3 < 3; o3++)
                coords[i * 3 + o3] += red2[o3] + red2[3 + o3] + bu_l[o3];
        }
    }
}

// ---------------------------------------------------------------------- driver
extern "C" void kernel_launch(void* const* d_in, const int* in_sizes, int n_in,
                              void* d_out, int out_size, void* d_ws, size_t ws_size,
                              hipStream_t stream)
{
    const float* s_in = (const float*)d_in[0];
    const float* z    = (const float*)d_in[1];
    const float* Wq   = (const float*)d_in[2];
    const float* bq   = (const float*)d_in[3];
    const float* Wk   = (const float*)d_in[4];
    const float* bk   = (const float*)d_in[5];
    const float* Wv   = (const float*)d_in[6];
    const float* bv   = (const float*)d_in[7];
    const float* Wb   = (const float*)d_in[8];
    const float* bb   = (const float*)d_in[9];
    const float* Wo   = (const float*)d_in[10];
    const float* bo   = (const float*)d_in[11];
    const float* Wt1  = (const float*)d_in[12];
    const float* bt1  = (const float*)d_in[13];
    const float* Wt2  = (const float*)d_in[14];
    const float* bt2  = (const float*)d_in[15];
    const float* Wu   = (const float*)d_in[16];
    const float* bu   = (const float*)d_in[17];
    const float* lng  = (const float*)d_in[18];
    const float* lnb  = (const float*)d_in[19];
    float* coords = (float*)d_out;

    // ---- workspace carve (~163 MB) ----
    float* wsf   = (float*)d_ws;
    float* qkv   = wsf;                              // N*QKVN
    float* tmp2  = qkv + (size_t)N * QKVN;           // 9*N*CS (split-K parts)
    float* scur  = tmp2 + (size_t)9 * N * CS;        // N*CS
    float* bqkv  = scur + (size_t)N * CS;            // L*QKVN
    ushort* wsu     = (ushort*)(bqkv + (size_t)L * QKVN);
    ushort* bias_all= wsu;                           // MB*N*N  bf16
    ushort* z_t     = bias_all + (size_t)MB * NN2;   // N*CZ*N (z transposed per i)
    ushort* WqkvT   = z_t + (size_t)N * CZ * N;
    ushort* WoT     = WqkvT + (size_t)L * CS * QKVN;
    ushort* Wt1T    = WoT + (size_t)L * OD * CS;
    ushort* Wt2T    = Wt1T + (size_t)L * CS * FF;
    ushort* WbT     = Wt2T + (size_t)L * FF * CS;    // MB*CZ
    ushort* scur_bf = WbT + (size_t)MB * CZ;         // N*CS
    ushort* obuf_bf = scur_bf + (size_t)N * CS;      // N*OD
    ushort* tmp1_bf = obuf_bf + (size_t)N * OD;      // N*FF
    (void)in_sizes; (void)n_in; (void)out_size; (void)ws_size;

    hipMemsetAsync(coords, 0, (size_t)N * 3 * sizeof(float), stream);
    init_s<<<(N * CS) / 256, 256, 0, stream>>>(s_in, scur, scur_bf);
    pack_bqkv<<<(L * QKVN + 255) / 256, 256, 0, stream>>>(bq, bk, bv, bqkv);
    pack_qkv_t<<<dim3(CS / 32, QKVN / 32, L), 256, 0, stream>>>(Wq, Wk, Wv, WqkvT);
    transpose_w<<<dim3(OD / 32, CS / 32, L), 256, 0, stream>>>(Wo, WoT, OD, CS);
    transpose_w<<<dim3(CS / 32, FF / 32, L), 256, 0, stream>>>(Wt1, Wt1T, CS, FF);
    transpose_w<<<dim3(FF / 32, CS / 32, L), 256, 0, stream>>>(Wt2, Wt2T, FF, CS);
    transpose_w<<<dim3(N / 32, CZ / 32, N), 256, 0, stream>>>(z, z_t, N, CZ);   // z_t[i][c][j]
    pack_wbt<<<(MB * CZ) / 256, 256, 0, stream>>>(Wb, WbT);
    bias_gemm<<<(int)(NN2 / 256), 256, 0, stream>>>(WbT, z, bb, bias_all);

    for (int r = 0; r < RECY; r++) {
        for (int l = 0; l < L; l++) {
            // qkv = s @ Wqkv + bqkv            (M=512, N=576, K=384)
            gemm_bf16<<<dim3(QKVN / 64, N / 64, 1), 256, 0, stream>>>(
                scur_bf, WqkvT + (size_t)l * CS * QKVN, bqkv + l * QKVN,
                qkv, nullptr, N, QKVN, CS, CS, 0);
            attn_fused<<<N, 256, 0, stream>>>(
                qkv, bias_all + (size_t)l * H * NN2, coords, z_t, obuf_bf);
            // o @ Wo (split-K 9)               (M=512, N=384, K=1728)
            gemm_bf16<<<dim3(CS / 64, N / 64, 9), 256, 0, stream>>>(
                obuf_bf, WoT + (size_t)l * OD * CS, nullptr,
                tmp2, nullptr, N, CS, OD, OD / 9, 0);
            ln_residual<<<N, 128, 0, stream>>>(
                tmp2, 9, bo + l * CS, scur, scur_bf,
                lng + (size_t)(2 * l) * CS, lnb + (size_t)(2 * l) * CS,
                nullptr, nullptr, nullptr);
            // FFN1: relu(s @ Wt1 + bt1) -> bf16 only   (M=512, N=1536, K=384)
            gemm_bf16<<<dim3(FF / 64, N / 64, 1), 256, 0, stream>>>(
                scur_bf, Wt1T + (size_t)l * CS * FF, bt1 + l * FF,
                nullptr, tmp1_bf, N, FF, CS, CS, 1);
            // FFN2 (split-K 8)                 (M=512, N=384, K=1536)
            gemm_bf16<<<dim3(CS / 64, N / 64, 8), 256, 0, stream>>>(
                tmp1_bf, Wt2T + (size_t)l * FF * CS, nullptr,
                tmp2, nullptr, N, CS, FF, FF / 8, 0);
            // LN2 + fused coord update
            ln_residual<<<N, 128, 0, stream>>>(
                tmp2, 8, bt2 + l * CS, scur, scur_bf,
                lng + (size_t)(2 * l + 1) * CS, lnb + (size_t)(2 * l + 1) * CS,
                Wu + (size_t)l * CS * 6, bu + l * 6, coords);
        }
    }
}